// Round 2
// 380.176 us; speedup vs baseline: 1.0980x; 1.0980x over previous
//
#include <hip/hip_runtime.h>
#include <cstdint>
#include <cstddef>

#define Tt 2048
#define Cc 1024
#define Ss 256

using short8 = __attribute__((ext_vector_type(8))) short;
using f32x4  = __attribute__((ext_vector_type(4))) float;
typedef const __attribute__((address_space(1))) void* as1_cvp;
typedef __attribute__((address_space(3))) void* as3_vp;

__device__ __forceinline__ unsigned short f2bf(float f) {
  unsigned int u = __float_as_uint(f);
  u += 0x7fffu + ((u >> 16) & 1u);
  return (unsigned short)(u >> 16);
}
__device__ __forceinline__ float bf2f(unsigned short h) {
  return __uint_as_float(((unsigned)h) << 16);
}
// 3-way split: v = h + m + l to ~2^-24 relative
__device__ __forceinline__ void split3(float v, unsigned short& h, unsigned short& m, unsigned short& l) {
  h = f2bf(v);
  float r = v - bf2f(h);
  m = f2bf(r);
  l = f2bf(r - bf2f(m));
}

// LDS short-offset for 64-row x 32-short tile, chunk-XOR swizzled (2-way bank
// aliasing on ds_read_b128 = free, m136)
__device__ __forceinline__ int sw32(int row, int q) {
  return row * 32 + ((q ^ ((row >> 1) & 3)) << 3);
}

// slots planes = split3(mean over 8 consecutive t rows)
__global__ __launch_bounds__(256) void poolsplit_k(const float* __restrict__ x, unsigned short* __restrict__ sp) {
  const long PS2 = 2048l * 1024;
  const int sli = blockIdx.x;           // b*256+s
  const int c = threadIdx.x << 2;
  const float* src = x + (size_t)sli * 8 * Cc + c;
  float a[4] = {0.f, 0.f, 0.f, 0.f};
#pragma unroll
  for (int j = 0; j < 8; j++) {
    float4 v = *(const float4*)(src + (size_t)j * Cc);
    a[0] += v.x; a[1] += v.y; a[2] += v.z; a[3] += v.w;
  }
  unsigned short h[4], m[4], l[4];
#pragma unroll
  for (int e = 0; e < 4; e++) split3(a[e] * 0.125f, h[e], m[e], l[e]);
  size_t o = (size_t)sli * Cc + c;
  *(uint2*)&sp[o]           = uint2{(unsigned)h[0] | ((unsigned)h[1] << 16), (unsigned)h[2] | ((unsigned)h[3] << 16)};
  *(uint2*)&sp[o + PS2]     = uint2{(unsigned)m[0] | ((unsigned)m[1] << 16), (unsigned)m[2] | ((unsigned)m[3] << 16)};
  *(uint2*)&sp[o + 2 * PS2] = uint2{(unsigned)l[0] | ((unsigned)l[1] << 16), (unsigned)l[2] | ((unsigned)l[3] << 16)};
}

// Transpose + split: dst[p][e][d] = split3(src[d][e]), npl planes written.
__global__ __launch_bounds__(256) void split_t_k(const float* __restrict__ src, unsigned short* __restrict__ dst,
                                                 long pstride, int npl) {
  __shared__ unsigned short th[64][68], tm[64][68], tl[64][68];
  const int r0 = blockIdx.y << 6, c0 = blockIdx.x << 6;
  const int tid = threadIdx.x;
#pragma unroll
  for (int p = 0; p < 4; p++) {
    int r = (p << 4) + (tid >> 4);
    int c = (tid & 15) << 2;
    float4 v = *(const float4*)&src[(size_t)(r0 + r) * Cc + c0 + c];
    unsigned short h, m, l;
    split3(v.x, h, m, l); th[c + 0][r] = h; tm[c + 0][r] = m; tl[c + 0][r] = l;
    split3(v.y, h, m, l); th[c + 1][r] = h; tm[c + 1][r] = m; tl[c + 1][r] = l;
    split3(v.z, h, m, l); th[c + 2][r] = h; tm[c + 2][r] = m; tl[c + 2][r] = l;
    split3(v.w, h, m, l); th[c + 3][r] = h; tm[c + 3][r] = m; tl[c + 3][r] = l;
  }
  __syncthreads();
#pragma unroll
  for (int p = 0; p < 4; p++) {
    int r = (p << 4) + (tid >> 4);      // dst row = src col
    int c = (tid & 15) << 2;
    size_t o = (size_t)(c0 + r) * Cc + r0 + c;
    *(uint2*)&dst[o] = uint2{(unsigned)th[r][c] | ((unsigned)th[r][c+1] << 16),
                             (unsigned)th[r][c+2] | ((unsigned)th[r][c+3] << 16)};
    *(uint2*)&dst[o + pstride] = uint2{(unsigned)tm[r][c] | ((unsigned)tm[r][c+1] << 16),
                                       (unsigned)tm[r][c+2] | ((unsigned)tm[r][c+3] << 16)};
    if (npl == 3)
      *(uint2*)&dst[o + 2 * pstride] = uint2{(unsigned)tl[r][c] | ((unsigned)tl[r][c+1] << 16),
                                             (unsigned)tl[r][c+2] | ((unsigned)tl[r][c+3] << 16)};
  }
}

// Plain split, npl planes
__global__ __launch_bounds__(256) void split_k(const float* __restrict__ src, unsigned short* __restrict__ dst,
                                               long pstride, int npl) {
  int id = blockIdx.x * 256 + threadIdx.x;
  int c = id << 2;
  float4 v = *(const float4*)&src[c];
  unsigned short h[4], m[4], l[4];
  split3(v.x, h[0], m[0], l[0]); split3(v.y, h[1], m[1], l[1]);
  split3(v.z, h[2], m[2], l[2]); split3(v.w, h[3], m[3], l[3]);
  *(uint2*)&dst[c] = uint2{(unsigned)h[0] | ((unsigned)h[1] << 16), (unsigned)h[2] | ((unsigned)h[3] << 16)};
  *(uint2*)&dst[c + pstride] = uint2{(unsigned)m[0] | ((unsigned)m[1] << 16), (unsigned)m[2] | ((unsigned)m[3] << 16)};
  if (npl == 3)
    *(uint2*)&dst[c + 2 * pstride] = uint2{(unsigned)l[0] | ((unsigned)l[1] << 16), (unsigned)l[2] | ((unsigned)l[3] << 16)};
}

// Multi-plane split GEMM body: C = scale * A @ B^T with A,B as NPL bf16 planes.
// NT=6: products hh,hm,mh,hl,lh,mm (error ~2^-24). NT=3: hh,hm,mh (~2^-16).
// 64x64 tile, BK=32, 4 waves of 32x32. global_load_lds width-16 staging,
// double-buffered (T3 minimum 2-phase): issue next K-tile's loads before
// computing the current one; the single __syncthreads() per step drains vmcnt
// after compute has covered most of the load latency.
template<int NT, int SPLIT_OUT>
__device__ __forceinline__ void gemm3_body(const unsigned short* __restrict__ Ap, long apl,
                                           const unsigned short* __restrict__ Bp, long bpl,
                                           float* __restrict__ C,
                                           unsigned short* __restrict__ Cs, long cpl,
                                           float scale) {
  constexpr int NPL = (NT == 6) ? 3 : 2;
  constexpr int BUFS = 2 * NPL * 2048;              // shorts per buffer
  __shared__ unsigned short LDS[2 * BUFS];          // double-buffered A+B planes
  const int tid = threadIdx.x, lane = tid & 63, wid = tid >> 6;
  const int m0 = blockIdx.y << 6, n0 = blockIdx.x << 6;

  const unsigned short* sp[2 * NPL];
  int dof[2 * NPL];                                  // byte offset within a buffer
#pragma unroll
  for (int i = 0; i < 2 * NPL; i++) {
    int s = wid * 2 * NPL + i;           // [0, 8*NPL)
    int tile = s >> 2;                   // [0, 2*NPL)
    int ci = ((s & 3) << 6) | lane;      // chunk in tile [0,256)
    int row = ci >> 2;
    int q = (ci & 3) ^ ((row >> 1) & 3); // source chunk for swizzled slot
    int isB = tile >= NPL;
    int pl = isB ? tile - NPL : tile;
    const unsigned short* base = isB ? (Bp + (size_t)pl * bpl) : (Ap + (size_t)pl * apl);
    int r0 = isB ? n0 : m0;
    sp[i] = base + (size_t)(r0 + row) * Cc + (q << 3);
    dof[i] = (tile * 2048 + ((s & 3) << 9)) * 2;
  }

  const int wm = (wid >> 1) << 5, wn = (wid & 1) << 5;
  const int lm = lane & 15, lq = lane >> 4;
  constexpr int PA[6] = {0, 0, 1, 0, 2, 1};
  constexpr int PB[6] = {0, 1, 0, 2, 0, 1};
  const f32x4 zero = {0.f, 0.f, 0.f, 0.f};
  f32x4 acc[2][2] = {{zero, zero}, {zero, zero}};

  // prologue: stage K-tile 0 into buf 0
#pragma unroll
  for (int i = 0; i < 2 * NPL; i++) {
    __builtin_amdgcn_global_load_lds((as1_cvp)sp[i], (as3_vp)((char*)LDS + dof[i]), 16, 0, 0);
    sp[i] += 32;
  }
  __syncthreads();

  int cur = 0;
  for (int k0 = 0; k0 < Cc; k0 += 32) {
    if (k0 + 32 < Cc) {                  // issue next tile's loads (prefetch)
      const int nb = (cur ^ 1) * (BUFS * 2);
#pragma unroll
      for (int i = 0; i < 2 * NPL; i++) {
        __builtin_amdgcn_global_load_lds((as1_cvp)sp[i], (as3_vp)((char*)LDS + nb + dof[i]), 16, 0, 0);
        sp[i] += 32;
      }
    }
    const int cb = cur * BUFS;           // shorts
    short8 af[2][NPL], bf[2][NPL];
#pragma unroll
    for (int i = 0; i < 2; i++)
#pragma unroll
      for (int p = 0; p < NPL; p++) {
        af[i][p] = *(const short8*)&LDS[cb + p * 2048 + sw32(wm + (i << 4) + lm, lq)];
        bf[i][p] = *(const short8*)&LDS[cb + (NPL + p) * 2048 + sw32(wn + (i << 4) + lm, lq)];
      }
#pragma unroll
    for (int i = 0; i < 2; i++)
#pragma unroll
      for (int j = 0; j < 2; j++)
#pragma unroll
        for (int t = 0; t < NT; t++)
          acc[i][j] = __builtin_amdgcn_mfma_f32_16x16x32_bf16(af[i][PA[t]], bf[j][PB[t]], acc[i][j], 0, 0, 0);
    __syncthreads();                     // drains vmcnt(0): next buf staged
    cur ^= 1;
  }
  // C/D: col = lane&15, row = (lane>>4)*4 + reg  [m89-verified]
#pragma unroll
  for (int i = 0; i < 2; i++)
#pragma unroll
    for (int j = 0; j < 2; j++)
#pragma unroll
      for (int r = 0; r < 4; r++) {
        int gr = m0 + wm + (i << 4) + (lq << 2) + r;
        int gc = n0 + wn + (j << 4) + lm;
        size_t o = (size_t)gr * Cc + gc;
        float v = acc[i][j][r] * scale;
        if (SPLIT_OUT) {
          unsigned short h = f2bf(v);
          float rr = v - bf2f(h);
          unsigned short mm2 = f2bf(rr);
          Cs[o] = h;
          Cs[o + cpl] = mm2;
          if (NPL == 3) Cs[o + 2 * (size_t)cpl] = f2bf(rr - bf2f(mm2));
        } else {
          C[o] = v;
        }
      }
}

// Concrete wrappers (no template __global__ — see round-5 link failure)
__global__ __launch_bounds__(256) void gemm3_61_k(const unsigned short* __restrict__ Ap, long apl,
                                                  const unsigned short* __restrict__ Bp, long bpl,
                                                  unsigned short* __restrict__ Cs, long cpl, float scale) {
  gemm3_body<6, 1>(Ap, apl, Bp, bpl, nullptr, Cs, cpl, scale);
}
__global__ __launch_bounds__(256) void gemm3_31_k(const unsigned short* __restrict__ Ap, long apl,
                                                  const unsigned short* __restrict__ Bp, long bpl,
                                                  unsigned short* __restrict__ Cs, long cpl, float scale) {
  gemm3_body<3, 1>(Ap, apl, Bp, bpl, nullptr, Cs, cpl, scale);
}
__global__ __launch_bounds__(256) void gemm3_30_k(const unsigned short* __restrict__ Ap, long apl,
                                                  const unsigned short* __restrict__ Bp, long bpl,
                                                  float* __restrict__ C, float scale) {
  gemm3_body<3, 0>(Ap, apl, Bp, bpl, C, nullptr, 0, scale);
}

// Fused scores + top-8 + softmax. 64 t-rows x 256 slots per block, 512 thr
// (8 waves of 32x64). BK=32, double-buffered 2-phase pipeline:
//   - kq: 3 planes via global_load_lds into LDS buf[2] (48 KB each)
//   - x:  fp32 tile staged to REGISTERS (float4/thread), split3'd into padded
//         LDS planes buf[2] AFTER the MFMA cluster (T14-style issue-early /
//         write-late) — no fp32 LDS tile, one barrier per K-step.
// LDS: kq 2*49152 + xplanes 2*13824 = 125952 B. Scores tail (64x260 f32)
// aliases the kq buffers after the K-loop.
// Grid: 256 1-D blocks, b = bid&7 so each batch's blocks land on one XCD
// (round-robin dispatch) -> kq slice (1.5 MB/batch) stays L2-local.
__global__ __launch_bounds__(512) void scores_topk_k(const float* __restrict__ x,
                                                     const unsigned short* __restrict__ kqp,
                                                     float* __restrict__ topw, int* __restrict__ topi) {
  __shared__ __align__(16) char smem[125952];
  unsigned short* lds16 = (unsigned short*)smem;
  float* sc = (float*)smem;                         // tail: 64x260 fp32

  const int tid = threadIdx.x, lane = tid & 63, wid = tid >> 6;
  const int bid = blockIdx.x;
  const int b = bid & 7, tt = bid >> 3;

  // kq staging: 48 slots (3 planes x 16 sub-tiles), 6 per wave
  const char* ksrc[6];
  int kdst[6];                                      // byte offset within a kq buffer
#pragma unroll
  for (int i = 0; i < 6; i++) {
    int s = wid * 6 + i;                 // [0,48)
    int p = s >> 4, sub = s & 15;
    int ci = (sub << 6) | lane;          // [0,1024)
    int row = ci >> 2;
    int q = (ci & 3) ^ ((row >> 1) & 3);
    ksrc[i] = (const char*)(kqp + (size_t)p * (2048l * 1024) + ((size_t)b * Ss + row) * Cc + (q << 3));
    kdst[i] = p * 16384 + sub * 1024;
  }
  const int spr = tid >> 3, spk = (tid & 7) << 2;   // x-tile: row, col(4 floats)
  const float* xsrc = x + ((size_t)b * Tt + (size_t)tt * 64 + spr) * Cc + spk;

  const int wm = (wid & 1) << 5;         // row group
  const int wn = (wid >> 1) << 6;        // col group (x4)
  const int lm = lane & 15, lq = lane >> 4;
  const int XP = 49152;                  // x-plane base (shorts); buf stride 6912, plane stride 2304

  constexpr int PA[6] = {0, 0, 1, 0, 2, 1};
  constexpr int PB[6] = {0, 1, 0, 2, 0, 1};
  const f32x4 zero = {0.f, 0.f, 0.f, 0.f};
  f32x4 acc[2][4];
#pragma unroll
  for (int i = 0; i < 2; i++)
#pragma unroll
    for (int j = 0; j < 4; j++) acc[i][j] = zero;

  // ---- prologue: stage K-tile 0 (x -> regs -> split -> planes buf0; kq -> buf0)
  {
    float4 xv = *(const float4*)xsrc; xsrc += 32;
#pragma unroll
    for (int i = 0; i < 6; i++) {
      __builtin_amdgcn_global_load_lds((as1_cvp)ksrc[i], (as3_vp)(smem + kdst[i]), 16, 0, 0);
      ksrc[i] += 64;
    }
    unsigned short h[4], m[4], l[4];
    split3(xv.x, h[0], m[0], l[0]); split3(xv.y, h[1], m[1], l[1]);
    split3(xv.z, h[2], m[2], l[2]); split3(xv.w, h[3], m[3], l[3]);
    int o = XP + spr * 36 + spk;
    *(uint2*)&lds16[o]        = uint2{(unsigned)h[0] | ((unsigned)h[1] << 16), (unsigned)h[2] | ((unsigned)h[3] << 16)};
    *(uint2*)&lds16[o + 2304] = uint2{(unsigned)m[0] | ((unsigned)m[1] << 16), (unsigned)m[2] | ((unsigned)m[3] << 16)};
    *(uint2*)&lds16[o + 4608] = uint2{(unsigned)l[0] | ((unsigned)l[1] << 16), (unsigned)l[2] | ((unsigned)l[3] << 16)};
  }
  __syncthreads();

  int cur = 0;
  for (int ks = 0; ks < 32; ks++) {
    const int nb = cur ^ 1;
    float4 xv2;
    if (ks < 31) {                       // issue next tile's loads (prefetch)
      xv2 = *(const float4*)xsrc; xsrc += 32;
#pragma unroll
      for (int i = 0; i < 6; i++) {
        __builtin_amdgcn_global_load_lds((as1_cvp)ksrc[i], (as3_vp)(smem + nb * 49152 + kdst[i]), 16, 0, 0);
        ksrc[i] += 64;
      }
    }
    // ---- compute current tile
    const int xb = XP + cur * 6912;      // shorts
    const int kb = cur * 24576;          // shorts
    short8 afr[2][3], bfr[4][3];
#pragma unroll
    for (int i = 0; i < 2; i++)
#pragma unroll
      for (int p = 0; p < 3; p++)
        afr[i][p] = *(const short8*)&lds16[xb + p * 2304 + (wm + (i << 4) + lm) * 36 + (lq << 3)];
#pragma unroll
    for (int j = 0; j < 4; j++) {
      int br = wn + (j << 4) + lm;
      int bo = (br << 5) + ((lq ^ ((br >> 1) & 3)) << 3);
#pragma unroll
      for (int p = 0; p < 3; p++)
        bfr[j][p] = *(const short8*)&lds16[kb + p * 8192 + bo];
    }
#pragma unroll
    for (int i = 0; i < 2; i++)
#pragma unroll
      for (int j = 0; j < 4; j++)
#pragma unroll
        for (int t = 0; t < 6; t++)
          acc[i][j] = __builtin_amdgcn_mfma_f32_16x16x32_bf16(afr[i][PA[t]], bfr[j][PB[t]], acc[i][j], 0, 0, 0);
    // ---- split next x tile into planes buf nb (write-late; regs only)
    if (ks < 31) {
      unsigned short h[4], m[4], l[4];
      split3(xv2.x, h[0], m[0], l[0]); split3(xv2.y, h[1], m[1], l[1]);
      split3(xv2.z, h[2], m[2], l[2]); split3(xv2.w, h[3], m[3], l[3]);
      int o = XP + nb * 6912 + spr * 36 + spk;
      *(uint2*)&lds16[o]        = uint2{(unsigned)h[0] | ((unsigned)h[1] << 16), (unsigned)h[2] | ((unsigned)h[3] << 16)};
      *(uint2*)&lds16[o + 2304] = uint2{(unsigned)m[0] | ((unsigned)m[1] << 16), (unsigned)m[2] | ((unsigned)m[3] << 16)};
      *(uint2*)&lds16[o + 4608] = uint2{(unsigned)l[0] | ((unsigned)l[1] << 16), (unsigned)l[2] | ((unsigned)l[3] << 16)};
    }
    __syncthreads();                     // drains vmcnt(0): kq buf nb staged; plane writes visible
    cur ^= 1;
  }

  // scores -> LDS (scaled 1/32), then per-wave top-8 + softmax
#pragma unroll
  for (int i = 0; i < 2; i++)
#pragma unroll
    for (int j = 0; j < 4; j++)
#pragma unroll
      for (int r = 0; r < 4; r++)
        sc[(wm + (i << 4) + (lq << 2) + r) * 260 + wn + (j << 4) + lm] = acc[i][j][r] * 0.03125f;
  __syncthreads();

  for (int r2 = 0; r2 < 8; r2++) {
    int row = (wid << 3) + r2;
    float4 v = *(const float4*)(sc + row * 260 + (lane << 2));
    float cand[4] = {v.x, v.y, v.z, v.w};
    float topv[8]; int tops[8];
#pragma unroll
    for (int k = 0; k < 8; k++) {
      float bv = -1e30f; int bs = 1 << 20;
#pragma unroll
      for (int e = 0; e < 4; e++) {
        int s = (lane << 2) + e;
        if (cand[e] > bv || (cand[e] == bv && s < bs)) { bv = cand[e]; bs = s; }
      }
#pragma unroll
      for (int m = 32; m >= 1; m >>= 1) {
        float ov = __shfl_xor(bv, m, 64);
        int   os = __shfl_xor(bs, m, 64);
        if (ov > bv || (ov == bv && os < bs)) { bv = ov; bs = os; }
      }
      topv[k] = bv; tops[k] = bs;
      if ((bs >> 2) == lane) cand[bs & 3] = -1e30f;
    }
    float mx = topv[0];
    float sum = 0.f;
#pragma unroll
    for (int k = 0; k < 8; k++) sum += expf(topv[k] - mx);
    if (lane < 8) {
      float myv = topv[0]; int myi = tops[0];
#pragma unroll
      for (int k = 1; k < 8; k++) if (lane == k) { myv = topv[k]; myi = tops[k]; }
      size_t trow = (size_t)b * Tt + (size_t)tt * 64 + row;
      topw[trow * 8 + lane] = expf(myv - mx) / sum;
      topi[trow * 8 + lane] = myi;
    }
  }
}

// out[row,:] = 0.5 * sum_k w_k * u[b*256+idx_k, :]   (fp32)
__global__ __launch_bounds__(256) void gatherout_k(const float* __restrict__ u, const float* __restrict__ topw,
                                                   const int* __restrict__ topi, float* __restrict__ out) {
  __shared__ float w[8];
  __shared__ int  id8[8];
  const int row = blockIdx.x;
  const int b = row >> 11;
  if (threadIdx.x < 8) {
    w[threadIdx.x]   = topw[(size_t)row * 8 + threadIdx.x];
    id8[threadIdx.x] = topi[(size_t)row * 8 + threadIdx.x];
  }
  __syncthreads();
  int c = threadIdx.x << 2;
  float ax = 0.f, ay = 0.f, az = 0.f, aw = 0.f;
#pragma unroll
  for (int j = 0; j < 8; j++) {
    const float4 vv = *(const float4*)&u[((size_t)(b << 8) + id8[j]) * Cc + c];
    float wj = w[j];
    ax = fmaf(wj, vv.x, ax); ay = fmaf(wj, vv.y, ay);
    az = fmaf(wj, vv.z, az); aw = fmaf(wj, vv.w, aw);
  }
  *(float4*)&out[(size_t)row * Cc + c] = make_float4(ax * 0.5f, ay * 0.5f, az * 0.5f, aw * 0.5f);
}

extern "C" void kernel_launch(void* const* d_in, const int* in_sizes, int n_in,
                              void* d_out, int out_size, void* d_ws, size_t ws_size,
                              hipStream_t stream) {
  (void)in_sizes; (void)n_in; (void)out_size; (void)ws_size;
  const float* x  = (const float*)d_in[0];
  const float* Wq = (const float*)d_in[1];
  const float* Wk = (const float*)d_in[2];
  const float* Wv = (const float*)d_in[3];
  const float* Wp = (const float*)d_in[4];
  float* out = (float*)d_out;

  char* ws = (char*)d_ws;
  const size_t MB = 1ull << 20;
  const long PS1 = 1024l * 1024;   // plane stride, 1024x1024 (shorts)
  const long PS2 = 2048l * 1024;   // plane stride, 2048x1024 (shorts)
  unsigned short* slotp = (unsigned short*)(ws + 0 * MB);   // 12 MB: 3 planes [2048x1024]
  unsigned short* Wqt   = (unsigned short*)(ws + 12 * MB);  // 6 MB: 3 planes [c][d]
  unsigned short* Wkt   = (unsigned short*)(ws + 18 * MB);  // 6 MB: 3 planes [e][d]
  unsigned short* Wvt   = (unsigned short*)(ws + 24 * MB);  // 4 MB: 2 planes [e][d]
  unsigned short* Wpp   = (unsigned short*)(ws + 28 * MB);  // 4 MB: 2 planes [o][d]
  unsigned short* MtT   = (unsigned short*)(ws + 32 * MB);  // 6 MB: 3 planes [c][e] = (Wk^T Wq)^T
  unsigned short* kqp   = (unsigned short*)(ws + 38 * MB);  // 12 MB: 3 planes [2048x1024]
  unsigned short* W2p   = (unsigned short*)(ws + 50 * MB);  // 4 MB: 2 planes [o][e] = Wp@Wv
  float*          u     = (float*)(ws + 54 * MB);           // 8 MB fp32 [2048x1024]
  float*          topw  = (float*)(ws + 62 * MB);           // 0.5 MB
  int*            topi  = (int*)(ws + 62 * MB + 512 * 1024);// 0.5 MB -> 63 MB total (<=113 validated)

  // 1. pool + split3 slots (x read once here)
  poolsplit_k<<<2048, 256, 0, stream>>>(x, slotp);
  // 2. transpose+split weights
  split_t_k<<<dim3(16, 16), 256, 0, stream>>>(Wq, Wqt, PS1, 3);
  split_t_k<<<dim3(16, 16), 256, 0, stream>>>(Wk, Wkt, PS1, 3);
  split_t_k<<<dim3(16, 16), 256, 0, stream>>>(Wv, Wvt, PS1, 2);
  split_k<<<1024, 256, 0, stream>>>(Wp, Wpp, PS1, 2);
  // 3. MtT[c][e] = sum_d Wq[d][c]*Wk[d][e]   (6-product, split3 out)
  gemm3_61_k<<<dim3(16, 16), 256, 0, stream>>>(Wqt, PS1, Wkt, PS1, MtT, PS1, 1.0f);
  // 4. kq[s][c] = sum_e slots[s][e]*MtT[c][e] (6-product, split3 out)
  gemm3_61_k<<<dim3(16, 32), 256, 0, stream>>>(slotp, PS2, MtT, PS1, kqp, PS2, 1.0f);
  // 5. W2[o][e] = sum_d Wp[o][d]*Wvt[e][d]    (3-product, split2 out)
  gemm3_31_k<<<dim3(16, 16), 256, 0, stream>>>(Wpp, PS1, Wvt, PS1, W2p, PS1, 1.0f);
  // 6. u[s][o] = sum_e slots[s][e]*W2[o][e]   (3-product, fp32 out)
  gemm3_30_k<<<dim3(16, 32), 256, 0, stream>>>(slotp, PS2, W2p, PS1, u, 1.0f);
  // 7. fused scores (6-product, dbuf 2-phase) + top-8 + softmax
  scores_topk_k<<<256, 512, 0, stream>>>(x, kqp, topw, topi);
  // 8. gather + 0.5 scale
  gatherout_k<<<16384, 256, 0, stream>>>(u, topw, topi, out);
}